// Round 9
// baseline (834.897 us; speedup 1.0000x reference)
//
#include <hip/hip_runtime.h>
#include <hip/hip_bf16.h>

// NEmbNet R9 (= R8 with nontemporal-store compile fix: use clang ext_vector v4f,
// not HIP_vector_type float4).
// m97 GEMM core (proven best; R7 8-phase was null at K<=1024 shapes).
// Expert-grouping G=8 at full M=8192 per dispatch (8 launches total),
// XCD-chunk swizzle puts ONE EXPERT PER XCD (B panel 2MB L2-resident),
// h0/h1 L3-resident between layers; gemm2 widened to 128-row blocks;
// nontemporal stores for the never-re-read output.

typedef short v8s __attribute__((ext_vector_type(8)));
typedef float v4f __attribute__((ext_vector_type(4)));
using bf16 = __hip_bfloat16;

#define AS_GLOBAL __attribute__((address_space(1)))
#define AS_LDS    __attribute__((address_space(3)))

static constexpr int Mtot = 8192;
static constexpr int Fdim = 512;
static constexpr int Hdim = 1024;
static constexpr int Pdim = 64;
static constexpr int Aexp = 16;

__device__ __forceinline__ void gload_lds16(const void* g, void* l) {
  __builtin_amdgcn_global_load_lds((const AS_GLOBAL void*)g, (AS_LDS void*)l, 16, 0, 0);
}
__device__ __forceinline__ unsigned short bfu(float x) {
  bf16 h = __float2bfloat16(x);
  return *(unsigned short*)&h;
}
#define MFMA16(d, a, b) d = __builtin_amdgcn_mfma_f32_16x16x32_bf16(a, b, d, 0, 0, 0)
#define WAIT_VM6 asm volatile("s_waitcnt vmcnt(6)" ::: "memory")
#define WAIT_VM0 asm volatile("s_waitcnt vmcnt(0)" ::: "memory")
#define BAR() __builtin_amdgcn_s_barrier()

__device__ __forceinline__ void cvt_span(const float* __restrict__ src,
                                         unsigned short* __restrict__ dst, int n4,
                                         int gid, int nthr) {
  for (int i = gid; i < n4; i += nthr) {
    float4 v = ((const float4*)src)[i];
    ushort4 u;
    u.x = bfu(v.x); u.y = bfu(v.y); u.z = bfu(v.z); u.w = bfu(v.w);
    ((ushort4*)dst)[i] = u;
  }
}

// ---------------------------------------------------------------- cvt all inputs
__global__ void cvt_all_kernel(const float* __restrict__ s0, unsigned short* __restrict__ d0, int n0,
                               const float* __restrict__ s1, unsigned short* __restrict__ d1, int n1,
                               const float* __restrict__ s2, unsigned short* __restrict__ d2, int n2,
                               const float* __restrict__ s3, unsigned short* __restrict__ d3, int n3) {
  int gid = blockIdx.x * blockDim.x + threadIdx.x;
  int nthr = gridDim.x * blockDim.x;
  cvt_span(s0, d0, n0, gid, nthr);
  cvt_span(s1, d1, n1, gid, nthr);
  cvt_span(s2, d2, n2, gid, nthr);
  cvt_span(s3, d3, n3, gid, nthr);
}

// ---------------------------------------------------------------- identity fill (nontemporal)
__global__ void ident_kernel(float* __restrict__ outp) {
  const long total4 = (long)Mtot * Pdim * Pdim / 4;
  long i = blockIdx.x * 256 + threadIdx.x;
  const long stride = (long)gridDim.x * 256;
  for (; i < total4; i += stride) {
    long e = i * 4;
    int q = (int)(e & 63);
    int p = (int)((e >> 6) & 63);
    v4f v;
    v[0] = (p == q) ? 1.f : 0.f;
    v[1] = (p == q + 1) ? 1.f : 0.f;
    v[2] = (p == q + 2) ? 1.f : 0.f;
    v[3] = (p == q + 3) ? 1.f : 0.f;
    __builtin_nontemporal_store(v, (v4f*)&outp[e]);
  }
}

// ---------------------------------------------------------------- m97-style batched GEMM (R6 core, frozen)
// C[g-slice] = relu(A @ B^T + bias). 128x128, BK=64, 4 waves, T2 swizzle.
// Grid = 512*G blocks; decode: XCD-chunk -> g (512 blocks/expert) ->
// msup(16) -> ny(8) -> mloc(4). One expert per XCD when G=8.
template <int NT>  // K = NT*64 == A row stride
__global__ __launch_bounds__(256) void gemm97_kernel(
    const bf16* __restrict__ Ain, long aAmul,
    const bf16* __restrict__ Bw,
    const float* __restrict__ bias,
    bf16* __restrict__ Cout, long aCmul) {
  constexpr int K = NT * 64;
  __shared__ short lsA[128 * 64];
  __shared__ short lsB[128 * 64];
  const int t = threadIdx.x;
  const int nwg = gridDim.x;

  const int flat = blockIdx.x;
  const int perx = nwg >> 3;
  const int swz = (flat & 7) * perx + (flat >> 3);
  const int g = swz >> 9;           // /512
  const int e = swz & 511;
  const int msup = e >> 5;          // 0..15
  const int ny = (e >> 2) & 7;      // 0..7
  const int mloc = e & 3;           // 0..3
  const int mBase = (msup * 4 + mloc) * 128;
  const int nBase = ny * 128;

  const bf16* A0 = Ain + (size_t)g * aAmul;
  const bf16* B0 = Bw + (size_t)g * (1024 * K);
  const float* biasE = bias + g * 1024 + nBase;
  bf16* C0 = Cout + (size_t)g * aCmul + nBase;

  const int w = t >> 6, lane = t & 63;
  const int wm = w >> 1, wn = w & 1;
  const int lr = lane & 15, lk = lane >> 4;

  v4f acc[4][4];
#pragma unroll
  for (int m = 0; m < 4; ++m)
#pragma unroll
    for (int n = 0; n < 4; ++n) acc[m][n] = (v4f)(0.f);

  const int rowA = t >> 3;
  const int sg = (t & 7) ^ (rowA & 7);   // T2 pre-swizzled source granule
  const bf16* gA = A0 + (size_t)(mBase + rowA) * K + sg * 8;
  const bf16* gB = B0 + (size_t)(nBase + rowA) * K + sg * 8;

  for (int k0 = 0; k0 < K; k0 += 64) {
#pragma unroll
    for (int i = 0; i < 4; ++i) {
      gload_lds16(gA + (size_t)(i * 32) * K + k0, &lsA[i * 2048 + t * 8]);
      gload_lds16(gB + (size_t)(i * 32) * K + k0, &lsB[i * 2048 + t * 8]);
    }
    __syncthreads();
#pragma unroll
    for (int kk = 0; kk < 2; ++kk) {
      v8s af[4], bfr[4];
#pragma unroll
      for (int m = 0; m < 4; ++m) {
        const int row = wm * 64 + m * 16 + lr;
        af[m] = *(const v8s*)&lsA[row * 64 + ((((kk << 2) + lk) ^ (row & 7)) << 3)];
      }
#pragma unroll
      for (int n = 0; n < 4; ++n) {
        const int row = wn * 64 + n * 16 + lr;
        bfr[n] = *(const v8s*)&lsB[row * 64 + ((((kk << 2) + lk) ^ (row & 7)) << 3)];
      }
#pragma unroll
      for (int m = 0; m < 4; ++m)
#pragma unroll
        for (int n = 0; n < 4; ++n)
          MFMA16(acc[m][n], af[m], bfr[n]);
    }
    __syncthreads();
  }

#pragma unroll
  for (int n = 0; n < 4; ++n) {
    const int colIn = wn * 64 + n * 16 + lr;
    const float bv = biasE[colIn];
#pragma unroll
    for (int m = 0; m < 4; ++m) {
      const int row0 = mBase + wm * 64 + m * 16 + lk * 4;
#pragma unroll
      for (int j = 0; j < 4; ++j) {
        float v = acc[m][n][j] + bv;
        v = v > 0.f ? v : 0.f;
        C0[(size_t)(row0 + j) * 1024 + colIn] = __float2bfloat16(v);
      }
    }
  }
}

// ---------------------------------------------------------------- L3 + softmax + scatter
// 128 rows/block, 4 waves (wave w: rows w*32..w*32+31), K=1024, dbuf staging,
// X overlays staging after the loop. grid (Mtot/128, G).
__global__ __launch_bounds__(256) void gemm2_softmax_kernel(
    const bf16* __restrict__ h1, const bf16* __restrict__ W2b,
    const float* __restrict__ ltl, const int* __restrict__ lidx,
    const int* __restrict__ aidx, int aOffset, float* __restrict__ outp) {
  __shared__ char smem[49152];  // lsA 2x16KB | lsB 2x8KB ; X (34.8KB) overlays
  __shared__ int s_lidx[32];
  __shared__ int s_inv[64];
  __shared__ int s_arow;
  short* lsA = (short*)smem;                  // [buf*8192 + row*64 + c]
  short* lsB = (short*)(smem + 32768);        // [buf*4096 + row*64 + c]
  float(*X)[68] = (float(*)[68])smem;

  const int aLoc = blockIdx.y;
  const bf16* Ain = h1 + (size_t)aLoc * Mtot * Hdim;
  const bf16* Bw = W2b + (size_t)aLoc * Pdim * Hdim;
  const float* ltlE = ltl + (size_t)aLoc * Pdim;

  const int t = threadIdx.x;
  const int mBase = blockIdx.x * 128;
  const int w = t >> 6, lane = t & 63;
  const int lr = lane & 15, lk = lane >> 4;
  const int wm = w;  // 4 waves x 32 rows

  if (t < 64) s_inv[t] = -1;
  __syncthreads();
  if (t < 32) {
    int q = lidx[t];
    s_lidx[t] = q;
    s_inv[q] = t;
  }
  if (t == 0) s_arow = aidx[aOffset + aLoc];
  __syncthreads();

  const int srow = t >> 3;                  // 0..31
  const int sg = (t & 7) ^ (srow & 7);
  const bf16* gA = Ain + (size_t)(mBase + srow) * Hdim + sg * 8;
  const bf16* gB = Bw + (size_t)srow * Hdim + sg * 8;

  auto stage = [&](int buf, int kt) {
#pragma unroll
    for (int i = 0; i < 4; ++i)
      gload_lds16(gA + (size_t)(i * 32) * Hdim + kt * 64, &lsA[buf * 8192 + i * 2048 + t * 8]);
#pragma unroll
    for (int i = 0; i < 2; ++i)
      gload_lds16(gB + (size_t)(i * 32) * Hdim + kt * 64, &lsB[buf * 4096 + i * 2048 + t * 8]);
  };

  v4f acc[2][4];
#pragma unroll
  for (int m = 0; m < 2; ++m)
#pragma unroll
    for (int n = 0; n < 4; ++n) acc[m][n] = (v4f)(0.f);

  stage(0, 0);
  for (int kt = 0; kt < 16; ++kt) {
    const int buf = kt & 1;
    if (kt + 1 < 16) { stage(buf ^ 1, kt + 1); WAIT_VM6; } else { WAIT_VM0; }
    BAR();
#pragma unroll
    for (int ks = 0; ks < 2; ++ks) {
      v8s af[2], bfr[4];
#pragma unroll
      for (int m = 0; m < 2; ++m) {
        const int row = wm * 32 + m * 16 + lr;
        af[m] = *(const v8s*)&lsA[buf * 8192 + row * 64 + ((((ks << 2) + lk) ^ (lr & 7)) << 3)];
      }
#pragma unroll
      for (int n = 0; n < 4; ++n) {
        const int row = n * 16 + lr;
        bfr[n] = *(const v8s*)&lsB[buf * 4096 + row * 64 + ((((ks << 2) + lk) ^ (lr & 7)) << 3)];
      }
#pragma unroll
      for (int m = 0; m < 2; ++m)
#pragma unroll
        for (int n = 0; n < 4; ++n)
          MFMA16(acc[m][n], af[m], bfr[n]);
    }
    BAR();
  }

  // X overlays staging (all staging reads done; barrier above synced)
#pragma unroll
  for (int n = 0; n < 4; ++n) {
    const int col = n * 16 + lr;
    const float lc = ltlE[col];
#pragma unroll
    for (int m = 0; m < 2; ++m)
#pragma unroll
      for (int j = 0; j < 4; ++j)
        X[wm * 32 + m * 16 + lk * 4 + j][col] = acc[m][n][j] + lc;
  }
  __syncthreads();

  if (t < 128) {
    const int r = t;
    float mx = -1e30f;
#pragma unroll
    for (int l = 0; l < 32; ++l) mx = fmaxf(mx, X[r][s_lidx[l]]);
    float s = 0.f;
#pragma unroll
    for (int l = 0; l < 32; ++l) s += __expf(X[r][s_lidx[l]] - mx);
    const float rs = 1.f / s;
    const size_t obase = ((size_t)(mBase + r) * 64 + s_arow) * 64;
#pragma unroll
    for (int q0 = 0; q0 < 64; q0 += 4) {
      v4f v;
      v[0] = (s_inv[q0 + 0] >= 0) ? __expf(X[r][q0 + 0] - mx) * rs : 0.f;
      v[1] = (s_inv[q0 + 1] >= 0) ? __expf(X[r][q0 + 1] - mx) * rs : 0.f;
      v[2] = (s_inv[q0 + 2] >= 0) ? __expf(X[r][q0 + 2] - mx) * rs : 0.f;
      v[3] = (s_inv[q0 + 3] >= 0) ? __expf(X[r][q0 + 3] - mx) * rs : 0.f;
      __builtin_nontemporal_store(v, (v4f*)&outp[obase + q0]);
    }
  }
}

// ---------------------------------------------------------------- launch
extern "C" void kernel_launch(void* const* d_in, const int* in_sizes, int n_in,
                              void* d_out, int out_size, void* d_ws, size_t ws_size,
                              hipStream_t stream) {
  const float* state = (const float*)d_in[0];
  const float* W0 = (const float*)d_in[1];
  const float* b0 = (const float*)d_in[2];
  const float* W1 = (const float*)d_in[3];
  const float* b1 = (const float*)d_in[4];
  const float* W2 = (const float*)d_in[5];
  const float* ltl = (const float*)d_in[6];
  const int* lidx = (const int*)d_in[7];
  const int* aidx = (const int*)d_in[8];
  float* outp = (float*)d_out;

  // ws: stateb 8MiB | W0b 16 | W1b 32 | W2b 2 | h0 | h1 (G*16MiB each)
  char* ws = (char*)d_ws;
  bf16* stateb = (bf16*)ws;
  bf16* W0b = stateb + (size_t)Mtot * Fdim;
  bf16* W1b = W0b + (size_t)Aexp * Hdim * Fdim;
  bf16* W2b = W1b + (size_t)Aexp * Hdim * Hdim;
  bf16* h0 = W2b + (size_t)Aexp * Pdim * Hdim;
  const size_t fixedB = (size_t)(Mtot * Fdim + Aexp * Hdim * Fdim +
                                 Aexp * Hdim * Hdim + Aexp * Pdim * Hdim) * 2;
  int G = 8;  // experts per pass
  while (G > 1 && fixedB + (size_t)2 * G * Mtot * Hdim * 2 + 4096 > ws_size) G >>= 1;
  bf16* h1 = h0 + (size_t)G * Mtot * Hdim;
  const int passes = Aexp / G;

  ident_kernel<<<dim3(4096), dim3(256), 0, stream>>>(outp);
  cvt_all_kernel<<<dim3(2048), dim3(256), 0, stream>>>(
      state, (unsigned short*)stateb, Mtot * Fdim / 4,
      W0, (unsigned short*)W0b, Aexp * Hdim * Fdim / 4,
      W1, (unsigned short*)W1b, Aexp * Hdim * Hdim / 4,
      W2, (unsigned short*)W2b, Aexp * Pdim * Hdim / 4);

  for (int p = 0; p < passes; ++p) {
    // L1: h0[g][8192][1024] = relu(state @ W0[pG+g]^T + b0[pG+g])
    gemm97_kernel<Fdim / 64><<<dim3(512 * G), dim3(256), 0, stream>>>(
        stateb, 0L,
        W0b + (size_t)p * G * Hdim * Fdim,
        b0 + (size_t)p * G * Hdim,
        h0, (long)Mtot * Hdim);
    // L2: h1[g] = relu(h0[g] @ W1[pG+g]^T + b1[pG+g])
    gemm97_kernel<Hdim / 64><<<dim3(512 * G), dim3(256), 0, stream>>>(
        h0, (long)Mtot * Hdim,
        W1b + (size_t)p * G * Hdim * Hdim,
        b1 + (size_t)p * G * Hdim,
        h1, (long)Mtot * Hdim);
    // L3 + softmax + scatter
    gemm2_softmax_kernel<<<dim3(Mtot / 128, G), dim3(256), 0, stream>>>(
        h1, W2b + (size_t)p * G * Pdim * Hdim,
        ltl + (size_t)p * G * Pdim, lidx, aidx, p * G, outp);
  }
}

// Round 10
// 688.728 us; speedup vs baseline: 1.2122x; 1.2122x over previous
//
#include <hip/hip_runtime.h>
#include <hip/hip_bf16.h>

// NEmbNet R10: R6 structure (best: 622us) + (1) coalesced LDS-bounce epilogue in
// gemm97 (kills suspected write-allocate RMW: FETCH~=WRITE signature), (2) partial
// ident (skip active rows; gemm2 covers them), (3) R9's proven 128-row gemm2 + NT
// out stores. MC=2048 chunks, G=16 experts folded per dispatch.

typedef short v8s __attribute__((ext_vector_type(8)));
typedef float v4f __attribute__((ext_vector_type(4)));
using bf16 = __hip_bfloat16;

#define AS_GLOBAL __attribute__((address_space(1)))
#define AS_LDS    __attribute__((address_space(3)))

static constexpr int Mtot = 8192;
static constexpr int Fdim = 512;
static constexpr int Hdim = 1024;
static constexpr int Pdim = 64;
static constexpr int Aexp = 16;

__device__ __forceinline__ void gload_lds16(const void* g, void* l) {
  __builtin_amdgcn_global_load_lds((const AS_GLOBAL void*)g, (AS_LDS void*)l, 16, 0, 0);
}
__device__ __forceinline__ unsigned short bfu(float x) {
  bf16 h = __float2bfloat16(x);
  return *(unsigned short*)&h;
}
#define MFMA16(d, a, b) d = __builtin_amdgcn_mfma_f32_16x16x32_bf16(a, b, d, 0, 0, 0)
#define WAIT_VM6 asm volatile("s_waitcnt vmcnt(6)" ::: "memory")
#define WAIT_VM0 asm volatile("s_waitcnt vmcnt(0)" ::: "memory")
#define BAR() __builtin_amdgcn_s_barrier()

__device__ __forceinline__ void cvt_span(const float* __restrict__ src,
                                         unsigned short* __restrict__ dst, int n4,
                                         int gid, int nthr) {
  for (int i = gid; i < n4; i += nthr) {
    float4 v = ((const float4*)src)[i];
    ushort4 u;
    u.x = bfu(v.x); u.y = bfu(v.y); u.z = bfu(v.z); u.w = bfu(v.w);
    ((ushort4*)dst)[i] = u;
  }
}

// ---------------------------------------------------------------- cvt all inputs
__global__ void cvt_all_kernel(const float* __restrict__ s0, unsigned short* __restrict__ d0, int n0,
                               const float* __restrict__ s1, unsigned short* __restrict__ d1, int n1,
                               const float* __restrict__ s2, unsigned short* __restrict__ d2, int n2,
                               const float* __restrict__ s3, unsigned short* __restrict__ d3, int n3) {
  int gid = blockIdx.x * blockDim.x + threadIdx.x;
  int nthr = gridDim.x * blockDim.x;
  cvt_span(s0, d0, n0, gid, nthr);
  cvt_span(s1, d1, n1, gid, nthr);
  cvt_span(s2, d2, n2, gid, nthr);
  cvt_span(s3, d3, n3, gid, nthr);
}

// ---------------------------------------------------------------- partial identity fill
// Writes identity only for NON-active rows p (active rows are written by gemm2
// every call, so coverage stays complete and deterministic).
__global__ void ident_kernel(float* __restrict__ outp, const int* __restrict__ aidx) {
  unsigned long long act = 0;
#pragma unroll
  for (int i = 0; i < Aexp; ++i) act |= 1ull << (aidx[i] & 63);
  const long total4 = (long)Mtot * Pdim * Pdim / 4;
  long i = blockIdx.x * 256 + threadIdx.x;
  const long stride = (long)gridDim.x * 256;
  for (; i < total4; i += stride) {
    long e = i * 4;
    int q = (int)(e & 63);
    int p = (int)((e >> 6) & 63);
    if ((act >> p) & 1) continue;  // gemm2 owns this row
    v4f v;
    v[0] = (p == q) ? 1.f : 0.f;
    v[1] = (p == q + 1) ? 1.f : 0.f;
    v[2] = (p == q + 2) ? 1.f : 0.f;
    v[3] = (p == q + 3) ? 1.f : 0.f;
    __builtin_nontemporal_store(v, (v4f*)&outp[e]);
  }
}

// ---------------------------------------------------------------- m97-style batched GEMM
// C[g-slice] = relu(A @ B^T + bias). 128x128, BK=64, 4 waves, T2 swizzle (frozen
// from R6). NEW: coalesced epilogue via per-wave 8KB LDS bounce -> 8 x 1KB
// contiguous wave stores (was 128 scalar 2B stores/thread -> RMW suspicion).
template <int NT>  // K = NT*64 == A row stride
__global__ __launch_bounds__(256) void gemm97_kernel(
    const bf16* __restrict__ Ain, long aAmul,
    const bf16* __restrict__ Bw,
    const float* __restrict__ bias,
    bf16* __restrict__ Cout, long aCmul, int nbm) {
  constexpr int K = NT * 64;
  __shared__ short ls[2][128 * 64];  // [0]=A, [1]=B; reused as epilogue bounce
  short* lsA = ls[0];
  short* lsB = ls[1];
  const int t = threadIdx.x;
  const int nwg = nbm * 128;

  const int flat = blockIdx.x;
  const int perx = nwg >> 3;
  const int swz = (flat & 7) * perx + (flat >> 3);
  const int perg = nbm * 8;
  const int g = swz / perg;
  const int e = swz % perg;
  const int msup = e >> 5;
  const int ny = (e >> 2) & 7;
  const int mloc = e & 3;
  const int mBase = (msup * 4 + mloc) * 128;
  const int nBase = ny * 128;

  const bf16* A0 = Ain + (size_t)g * aAmul;
  const bf16* B0 = Bw + (size_t)g * (1024 * K);
  const float* biasE = bias + g * 1024 + nBase;
  bf16* C0 = Cout + (size_t)g * aCmul + nBase;

  const int w = t >> 6, lane = t & 63;
  const int wm = w >> 1, wn = w & 1;
  const int lr = lane & 15, lk = lane >> 4;

  v4f acc[4][4];
#pragma unroll
  for (int m = 0; m < 4; ++m)
#pragma unroll
    for (int n = 0; n < 4; ++n) acc[m][n] = (v4f)(0.f);

  const int rowA = t >> 3;
  const int sg = (t & 7) ^ (rowA & 7);   // T2 pre-swizzled source granule
  const bf16* gA = A0 + (size_t)(mBase + rowA) * K + sg * 8;
  const bf16* gB = B0 + (size_t)(nBase + rowA) * K + sg * 8;

  for (int k0 = 0; k0 < K; k0 += 64) {
#pragma unroll
    for (int i = 0; i < 4; ++i) {
      gload_lds16(gA + (size_t)(i * 32) * K + k0, &lsA[i * 2048 + t * 8]);
      gload_lds16(gB + (size_t)(i * 32) * K + k0, &lsB[i * 2048 + t * 8]);
    }
    __syncthreads();
#pragma unroll
    for (int kk = 0; kk < 2; ++kk) {
      v8s af[4], bfr[4];
#pragma unroll
      for (int m = 0; m < 4; ++m) {
        const int row = wm * 64 + m * 16 + lr;
        af[m] = *(const v8s*)&lsA[row * 64 + ((((kk << 2) + lk) ^ (row & 7)) << 3)];
      }
#pragma unroll
      for (int n = 0; n < 4; ++n) {
        const int row = wn * 64 + n * 16 + lr;
        bfr[n] = *(const v8s*)&lsB[row * 64 + ((((kk << 2) + lk) ^ (row & 7)) << 3)];
      }
#pragma unroll
      for (int m = 0; m < 4; ++m)
#pragma unroll
        for (int n = 0; n < 4; ++n)
          MFMA16(acc[m][n], af[m], bfr[n]);
    }
    __syncthreads();
  }

  // ---- coalesced epilogue: per-wave private 8KB bounce (64x64 u16, XOR-swizzled)
  unsigned short* wbuf = (unsigned short*)&ls[0][0] + w * 4096;
#pragma unroll
  for (int n = 0; n < 4; ++n) {
    const float bv = biasE[wn * 64 + n * 16 + lr];
#pragma unroll
    for (int m = 0; m < 4; ++m) {
#pragma unroll
      for (int j = 0; j < 4; ++j) {
        const int rl = m * 16 + lk * 4 + j;       // wave-local row 0..63
        const int cl = n * 16 + lr;               // wave-local col 0..63
        float v = acc[m][n][j] + bv;
        v = v > 0.f ? v : 0.f;
        wbuf[rl * 64 + (((cl >> 3) ^ (rl & 7)) << 3) + (cl & 7)] = bfu(v);
      }
    }
  }
  // readback: lane = rr*8? no: lane>>3 = row-in-group, lane&7 = granule
  const int rr = lane >> 3, gg = lane & 7;
#pragma unroll
  for (int r8 = 0; r8 < 8; ++r8) {
    const int rl = r8 * 8 + rr;
    v8s pk = *(const v8s*)&wbuf[rl * 64 + ((gg ^ (rl & 7)) << 3)];
    const int row = mBase + wm * 64 + rl;
    *(v8s*)&C0[(size_t)row * 1024 + wn * 64 + gg * 8] = pk;  // 8 rows x 128B contiguous / wave-store
  }
}

// ---------------------------------------------------------------- L3 + softmax + scatter
// 128 rows/block, 4 waves, K=1024, dbuf staging, X overlays staging (R9-proven).
__global__ __launch_bounds__(256) void gemm2_softmax_kernel(
    const bf16* __restrict__ h1, const bf16* __restrict__ W2b,
    const float* __restrict__ ltl, const int* __restrict__ lidx,
    const int* __restrict__ aidx, float* __restrict__ outp, int mGlobBase, int MC) {
  __shared__ char smem[49152];  // lsA 2x16KB | lsB 2x8KB ; X (34.8KB) overlays
  __shared__ int s_lidx[32];
  __shared__ int s_inv[64];
  __shared__ int s_arow;
  short* lsA = (short*)smem;
  short* lsB = (short*)(smem + 32768);
  float(*X)[68] = (float(*)[68])smem;

  const int aLoc = blockIdx.y;
  const bf16* Ain = h1 + (size_t)aLoc * MC * Hdim;
  const bf16* Bw = W2b + (size_t)aLoc * Pdim * Hdim;
  const float* ltlE = ltl + (size_t)aLoc * Pdim;

  const int t = threadIdx.x;
  const int mBase = blockIdx.x * 128;
  const int w = t >> 6, lane = t & 63;
  const int lr = lane & 15, lk = lane >> 4;
  const int wm = w;

  if (t < 64) s_inv[t] = -1;
  __syncthreads();
  if (t < 32) {
    int q = lidx[t];
    s_lidx[t] = q;
    s_inv[q] = t;
  }
  if (t == 0) s_arow = aidx[aLoc];
  __syncthreads();

  const int srow = t >> 3;
  const int sg = (t & 7) ^ (srow & 7);
  const bf16* gA = Ain + (size_t)(mBase + srow) * Hdim + sg * 8;
  const bf16* gB = Bw + (size_t)srow * Hdim + sg * 8;

  auto stage = [&](int buf, int kt) {
#pragma unroll
    for (int i = 0; i < 4; ++i)
      gload_lds16(gA + (size_t)(i * 32) * Hdim + kt * 64, &lsA[buf * 8192 + i * 2048 + t * 8]);
#pragma unroll
    for (int i = 0; i < 2; ++i)
      gload_lds16(gB + (size_t)(i * 32) * Hdim + kt * 64, &lsB[buf * 4096 + i * 2048 + t * 8]);
  };

  v4f acc[2][4];
#pragma unroll
  for (int m = 0; m < 2; ++m)
#pragma unroll
    for (int n = 0; n < 4; ++n) acc[m][n] = (v4f)(0.f);

  stage(0, 0);
  for (int kt = 0; kt < 16; ++kt) {
    const int buf = kt & 1;
    if (kt + 1 < 16) { stage(buf ^ 1, kt + 1); WAIT_VM6; } else { WAIT_VM0; }
    BAR();
#pragma unroll
    for (int ks = 0; ks < 2; ++ks) {
      v8s af[2], bfr[4];
#pragma unroll
      for (int m = 0; m < 2; ++m) {
        const int row = wm * 32 + m * 16 + lr;
        af[m] = *(const v8s*)&lsA[buf * 8192 + row * 64 + ((((ks << 2) + lk) ^ (lr & 7)) << 3)];
      }
#pragma unroll
      for (int n = 0; n < 4; ++n) {
        const int row = n * 16 + lr;
        bfr[n] = *(const v8s*)&lsB[buf * 4096 + row * 64 + ((((ks << 2) + lk) ^ (lr & 7)) << 3)];
      }
#pragma unroll
      for (int m = 0; m < 2; ++m)
#pragma unroll
        for (int n = 0; n < 4; ++n)
          MFMA16(acc[m][n], af[m], bfr[n]);
    }
    BAR();
  }

#pragma unroll
  for (int n = 0; n < 4; ++n) {
    const int col = n * 16 + lr;
    const float lc = ltlE[col];
#pragma unroll
    for (int m = 0; m < 2; ++m)
#pragma unroll
      for (int j = 0; j < 4; ++j)
        X[wm * 32 + m * 16 + lk * 4 + j][col] = acc[m][n][j] + lc;
  }
  __syncthreads();

  if (t < 128) {
    const int r = t;
    float mx = -1e30f;
#pragma unroll
    for (int l = 0; l < 32; ++l) mx = fmaxf(mx, X[r][s_lidx[l]]);
    float s = 0.f;
#pragma unroll
    for (int l = 0; l < 32; ++l) s += __expf(X[r][s_lidx[l]] - mx);
    const float rs = 1.f / s;
    const size_t obase = ((size_t)(mGlobBase + mBase + r) * 64 + s_arow) * 64;
#pragma unroll
    for (int q0 = 0; q0 < 64; q0 += 4) {
      v4f v;
      v[0] = (s_inv[q0 + 0] >= 0) ? __expf(X[r][q0 + 0] - mx) * rs : 0.f;
      v[1] = (s_inv[q0 + 1] >= 0) ? __expf(X[r][q0 + 1] - mx) * rs : 0.f;
      v[2] = (s_inv[q0 + 2] >= 0) ? __expf(X[r][q0 + 2] - mx) * rs : 0.f;
      v[3] = (s_inv[q0 + 3] >= 0) ? __expf(X[r][q0 + 3] - mx) * rs : 0.f;
      __builtin_nontemporal_store(v, (v4f*)&outp[obase + q0]);
    }
  }
}

// ---------------------------------------------------------------- launch
extern "C" void kernel_launch(void* const* d_in, const int* in_sizes, int n_in,
                              void* d_out, int out_size, void* d_ws, size_t ws_size,
                              hipStream_t stream) {
  const float* state = (const float*)d_in[0];
  const float* W0 = (const float*)d_in[1];
  const float* b0 = (const float*)d_in[2];
  const float* W1 = (const float*)d_in[3];
  const float* b1 = (const float*)d_in[4];
  const float* W2 = (const float*)d_in[5];
  const float* ltl = (const float*)d_in[6];
  const int* lidx = (const int*)d_in[7];
  const int* aidx = (const int*)d_in[8];
  float* outp = (float*)d_out;

  char* ws = (char*)d_ws;
  bf16* stateb = (bf16*)ws;
  bf16* W0b = stateb + (size_t)Mtot * Fdim;
  bf16* W1b = W0b + (size_t)Aexp * Hdim * Fdim;
  bf16* W2b = W1b + (size_t)Aexp * Hdim * Hdim;
  bf16* h0 = W2b + (size_t)Aexp * Pdim * Hdim;
  const size_t fixedB = (size_t)(Mtot * Fdim + Aexp * Hdim * Fdim +
                                 Aexp * Hdim * Hdim + Aexp * Pdim * Hdim) * 2;
  int MC = 2048;
  while (MC > 512 && fixedB + (size_t)2 * Aexp * MC * Hdim * 2 + 4096 > ws_size) MC >>= 1;
  bf16* h1 = h0 + (size_t)Aexp * MC * Hdim;

  ident_kernel<<<dim3(4096), dim3(256), 0, stream>>>(outp, aidx);
  cvt_all_kernel<<<dim3(2048), dim3(256), 0, stream>>>(
      state, (unsigned short*)stateb, Mtot * Fdim / 4,
      W0, (unsigned short*)W0b, Aexp * Hdim * Fdim / 4,
      W1, (unsigned short*)W1b, Aexp * Hdim * Hdim / 4,
      W2, (unsigned short*)W2b, Aexp * Pdim * Hdim / 4);

  const int nbm = MC / 128;
  for (int mOff = 0; mOff < Mtot; mOff += MC) {
    gemm97_kernel<Fdim / 64><<<dim3(nbm * 128), dim3(256), 0, stream>>>(
        stateb + (size_t)mOff * Fdim, 0L,
        W0b, b0, h0, (long)MC * Hdim, nbm);
    gemm97_kernel<Hdim / 64><<<dim3(nbm * 128), dim3(256), 0, stream>>>(
        h0, (long)MC * Hdim,
        W1b, b1, h1, (long)MC * Hdim, nbm);
    gemm2_softmax_kernel<<<dim3(MC / 128, Aexp), dim3(256), 0, stream>>>(
        h1, W2b, ltl, lidx, aidx, outp, mOff, MC);
  }
}